// Round 4
// baseline (229.293 us; speedup 1.0000x reference)
//
#include <hip/hip_runtime.h>

typedef __attribute__((ext_vector_type(8))) __bf16 bf16x8;
typedef __attribute__((ext_vector_type(4))) float f32x4;

#define DI   512
#define DO   512
#define XROW (128 * DI)   // floats between consecutive batch rows of x
#define OROW (128 * DO)

// A tile [128 m][64 k] bf16, 128 B/row. Reads: rows l16-spread -> (row&7) spreads 8.
__device__ __forceinline__ int swzA(int row, int kbyte) {
  return (row * 128 + kbyte) ^ ((row & 7) << 4);
}
// B tile [128 o][64 k] bf16. Writes land on rows 4L+c -> fold bits 2..4 so the
// 4-row groups spread across all 8 swizzle classes; fragment reads stay ~2-way.
__device__ __forceinline__ int swzB(int row, int kbyte) {
  return (row * 128 + kbyte) ^ (((row ^ (row >> 2)) & 7) << 4);
}

union FragU { bf16x8 b; };

__global__ __launch_bounds__(256, 4)   // 4 blocks/CU: TLP covers load latency
void nlinear_mfma(const float* __restrict__ xp, const float* __restrict__ wp,
                  const float* __restrict__ bp, float* __restrict__ op) {
  // XCD swizzle: the 8 tiles of one n land on one XCD (nwg=1024, %8==0)
  int blk = blockIdx.x;
  int L  = ((blk & 7) << 7) + (blk >> 3);
  int n  = L >> 3;
  int mt = (L >> 2) & 1;
  int ot = L & 3;
  int mBase = mt << 7;
  int oBase = ot << 7;

  __shared__ char ldsbuf[2 * 128 * 64 * 2];  // A tile + B tile, bf16 (32 KB)
  char* aLds = ldsbuf;
  char* bLds = ldsbuf + 128 * 64 * 2;

  int tid  = threadIdx.x;
  int wid  = tid >> 6;
  int lane = tid & 63;
  int wm  = (wid >> 1) << 6;
  int wn  = (wid & 1) << 6;
  int l16 = lane & 15;
  int l4  = lane >> 4;

  // A staging: thread t -> row m = t>>1, k-half (t&1)*32 (32 floats, 8xf32x4)
  int am  = tid >> 1;
  int akh = (tid & 1) << 5;
  const float* aSrc = xp + (size_t)(mBase + am) * XROW + n * DI + akh;

  // B staging: thread t -> o-cols [4*(t&31), +4), k-rows kg*8..+8 (8xf32x4)
  int ob = (tid & 31) << 2;
  int kg = tid >> 5;
  const float* bSrc = wp + ((size_t)n * DI + (kg << 3)) * DO + oBase + ob;

  f32x4 aReg[8];
  f32x4 bReg[8];

  f32x4 acc[4][4];
  #pragma unroll
  for (int i = 0; i < 4; ++i)
    #pragma unroll
    for (int j = 0; j < 4; ++j)
      acc[i][j] = f32x4{0.f, 0.f, 0.f, 0.f};

  auto loadA = [&](int kt) {
    #pragma unroll
    for (int i = 0; i < 8; ++i)
      aReg[i] = *(const f32x4*)(aSrc + kt * 64 + i * 4);
  };
  auto loadB = [&](int kt) {
    #pragma unroll
    for (int j = 0; j < 8; ++j)
      bReg[j] = *(const f32x4*)(bSrc + (size_t)(kt * 64 + j) * DO);
  };

  // native __bf16 casts -> v_cvt_pk_bf16_f32 (m240)
  auto writeA = [&]() {
    #pragma unroll
    for (int i2 = 0; i2 < 4; ++i2) {
      bf16x8 v;
      #pragma unroll
      for (int e = 0; e < 8; ++e)
        v[e] = (__bf16)aReg[i2 * 2 + (e >> 2)][e & 3];
      *(bf16x8*)(aLds + swzA(am, akh * 2 + i2 * 16)) = v;
    }
  };

  auto writeB = [&]() {
    #pragma unroll
    for (int c = 0; c < 4; ++c) {
      bf16x8 v;
      #pragma unroll
      for (int j = 0; j < 8; ++j)
        v[j] = (__bf16)bReg[j][c];
      *(bf16x8*)(bLds + swzB(ob + c, kg << 4)) = v;
    }
  };

  auto compute = [&]() {
    #pragma unroll
    for (int ks = 0; ks < 2; ++ks) {
      FragU af[4], bfr[4];
      #pragma unroll
      for (int i = 0; i < 4; ++i)
        af[i].b = *(const bf16x8*)(aLds + swzA(wm + i * 16 + l16, ks * 64 + l4 * 16));
      #pragma unroll
      for (int j = 0; j < 4; ++j)
        bfr[j].b = *(const bf16x8*)(bLds + swzB(wn + j * 16 + l16, ks * 64 + l4 * 16));
      #pragma unroll
      for (int i = 0; i < 4; ++i)
        #pragma unroll
        for (int j = 0; j < 4; ++j)
          acc[i][j] = __builtin_amdgcn_mfma_f32_16x16x32_bf16(
              af[i].b, bfr[j].b, acc[i][j], 0, 0, 0);
    }
  };

  // bias early: latency hidden under the main loop
  float bi[4];
  #pragma unroll
  for (int j = 0; j < 4; ++j)
    bi[j] = bp[n * DO + oBase + wn + j * 16 + l16];

  loadA(0); loadB(0);
  for (int kt = 0; kt < 8; ++kt) {
    __syncthreads();                 // prev tile's LDS reads done
    writeA();                        // vmcnt-waits this tile's loads
    writeB();
    if (kt < 7) { loadA(kt + 1); loadB(kt + 1); }  // issue BEFORE barrier:
    __syncthreads();                 // loads fly during barrier + compute
    compute();
  }

  // epilogue: D layout col = lane&15, row = (lane>>4)*4 + r (m89-verified)
  #pragma unroll
  for (int i = 0; i < 4; ++i) {
    #pragma unroll
    for (int j = 0; j < 4; ++j) {
      #pragma unroll
      for (int r = 0; r < 4; ++r) {
        int m = wm + i * 16 + l4 * 4 + r;
        int o = oBase + wn + j * 16 + l16;
        op[(size_t)(mBase + m) * OROW + n * DO + o] = acc[i][j][r] + bi[j];
      }
    }
  }
}

extern "C" void kernel_launch(void* const* d_in, const int* in_sizes, int n_in,
                              void* d_out, int out_size, void* d_ws, size_t ws_size,
                              hipStream_t stream) {
  const float* x = (const float*)d_in[0];
  const float* w = (const float*)d_in[1];
  const float* b = (const float*)d_in[2];
  float* o = (float*)d_out;
  hipLaunchKernelGGL(nlinear_mfma, dim3(1024), dim3(256), 0, stream, x, w, b, o);
}

// Round 5
// 94.117 us; speedup vs baseline: 2.4362x; 2.4362x over previous
//
#include <hip/hip_runtime.h>

typedef __attribute__((ext_vector_type(8))) __bf16 bf16x8;
typedef __attribute__((ext_vector_type(4))) float f32x4;

#define DI   512
#define DO   512
#define XROW (128 * DI)   // floats between consecutive batch rows of x
#define OROW (128 * DO)

// A tile [128 m][64 k] bf16, 128 B/row. Reads: rows l16-spread -> (row&7) spreads 8.
__device__ __forceinline__ int swzA(int row, int kbyte) {
  return (row * 128 + kbyte) ^ ((row & 7) << 4);
}
// B tile [128 o][64 k] bf16. Writes land on rows 4L+c -> fold bits 2..4 so the
// 4-row groups spread across all 8 swizzle classes; fragment reads stay ~2-way.
__device__ __forceinline__ int swzB(int row, int kbyte) {
  return (row * 128 + kbyte) ^ (((row ^ (row >> 2)) & 7) << 4);
}

union FragU { bf16x8 b; };

// 3 waves/EU: unified VGPR+AGPR budget 512/3=170 >= ~148 needed -> no spill.
// (256,4) capped the budget at 128 and spilled staging regs to scratch
// (VGPR 84->64, FETCH 100->354 MB, 60.8->229 us). Do NOT raise this without
// cutting register demand first.
__global__ __launch_bounds__(256, 3)
void nlinear_mfma(const float* __restrict__ xp, const float* __restrict__ wp,
                  const float* __restrict__ bp, float* __restrict__ op) {
  // XCD swizzle: the 8 tiles of one n land on one XCD (nwg=1024, %8==0)
  int blk = blockIdx.x;
  int L  = ((blk & 7) << 7) + (blk >> 3);
  int n  = L >> 3;
  int mt = (L >> 2) & 1;
  int ot = L & 3;
  int mBase = mt << 7;
  int oBase = ot << 7;

  __shared__ char ldsbuf[2 * 128 * 64 * 2];  // A tile + B tile, bf16 (32 KB)
  char* aLds = ldsbuf;
  char* bLds = ldsbuf + 128 * 64 * 2;

  int tid  = threadIdx.x;
  int wid  = tid >> 6;
  int lane = tid & 63;
  int wm  = (wid >> 1) << 6;
  int wn  = (wid & 1) << 6;
  int l16 = lane & 15;
  int l4  = lane >> 4;

  // A staging: thread t -> row m = t>>1, k-half (t&1)*32 (32 floats, 8xf32x4)
  int am  = tid >> 1;
  int akh = (tid & 1) << 5;
  const float* aSrc = xp + (size_t)(mBase + am) * XROW + n * DI + akh;

  // B staging: thread t -> o-cols [4*(t&31), +4), k-rows kg*8..+8 (8xf32x4)
  int ob = (tid & 31) << 2;
  int kg = tid >> 5;
  const float* bSrc = wp + ((size_t)n * DI + (kg << 3)) * DO + oBase + ob;

  f32x4 aReg[8];
  f32x4 bReg[8];

  f32x4 acc[4][4];
  #pragma unroll
  for (int i = 0; i < 4; ++i)
    #pragma unroll
    for (int j = 0; j < 4; ++j)
      acc[i][j] = f32x4{0.f, 0.f, 0.f, 0.f};

  auto loadA = [&](int kt) {
    #pragma unroll
    for (int i = 0; i < 8; ++i)
      aReg[i] = *(const f32x4*)(aSrc + kt * 64 + i * 4);
  };
  auto loadB = [&](int kt) {
    #pragma unroll
    for (int j = 0; j < 8; ++j)
      bReg[j] = *(const f32x4*)(bSrc + (size_t)(kt * 64 + j) * DO);
  };

  // native __bf16 casts -> v_cvt_pk_bf16_f32 (m240)
  auto writeA = [&]() {
    #pragma unroll
    for (int i2 = 0; i2 < 4; ++i2) {
      bf16x8 v;
      #pragma unroll
      for (int e = 0; e < 8; ++e)
        v[e] = (__bf16)aReg[i2 * 2 + (e >> 2)][e & 3];
      *(bf16x8*)(aLds + swzA(am, akh * 2 + i2 * 16)) = v;
    }
  };

  auto writeB = [&]() {
    #pragma unroll
    for (int c = 0; c < 4; ++c) {
      bf16x8 v;
      #pragma unroll
      for (int j = 0; j < 8; ++j)
        v[j] = (__bf16)bReg[j][c];
      *(bf16x8*)(bLds + swzB(ob + c, kg << 4)) = v;
    }
  };

  auto compute = [&]() {
    #pragma unroll
    for (int ks = 0; ks < 2; ++ks) {
      FragU af[4], bfr[4];
      #pragma unroll
      for (int i = 0; i < 4; ++i)
        af[i].b = *(const bf16x8*)(aLds + swzA(wm + i * 16 + l16, ks * 64 + l4 * 16));
      #pragma unroll
      for (int j = 0; j < 4; ++j)
        bfr[j].b = *(const bf16x8*)(bLds + swzB(wn + j * 16 + l16, ks * 64 + l4 * 16));
      #pragma unroll
      for (int i = 0; i < 4; ++i)
        #pragma unroll
        for (int j = 0; j < 4; ++j)
          acc[i][j] = __builtin_amdgcn_mfma_f32_16x16x32_bf16(
              af[i].b, bfr[j].b, acc[i][j], 0, 0, 0);
    }
  };

  // bias early: latency hidden under the main loop
  float bi[4];
  #pragma unroll
  for (int j = 0; j < 4; ++j)
    bi[j] = bp[n * DO + oBase + wn + j * 16 + l16];

  loadA(0); loadB(0);
  for (int kt = 0; kt < 8; ++kt) {
    __syncthreads();                 // prev tile's LDS reads done
    writeA();                        // vmcnt-waits this tile's loads
    writeB();
    if (kt < 7) { loadA(kt + 1); loadB(kt + 1); }  // issue BEFORE barrier:
    __syncthreads();                 // loads fly during barrier + compute
    compute();
  }

  // epilogue: D layout col = lane&15, row = (lane>>4)*4 + r (m89-verified)
  #pragma unroll
  for (int i = 0; i < 4; ++i) {
    #pragma unroll
    for (int j = 0; j < 4; ++j) {
      #pragma unroll
      for (int r = 0; r < 4; ++r) {
        int m = wm + i * 16 + l4 * 4 + r;
        int o = oBase + wn + j * 16 + l16;
        op[(size_t)(mBase + m) * OROW + n * DO + o] = acc[i][j][r] + bi[j];
      }
    }
  }
}

extern "C" void kernel_launch(void* const* d_in, const int* in_sizes, int n_in,
                              void* d_out, int out_size, void* d_ws, size_t ws_size,
                              hipStream_t stream) {
  const float* x = (const float*)d_in[0];
  const float* w = (const float*)d_in[1];
  const float* b = (const float*)d_in[2];
  float* o = (float*)d_out;
  hipLaunchKernelGGL(nlinear_mfma, dim3(1024), dim3(256), 0, stream, x, w, b, o);
}

// Round 6
// 54.442 us; speedup vs baseline: 4.2117x; 1.7288x over previous
//
#include <hip/hip_runtime.h>

typedef __attribute__((ext_vector_type(8))) __bf16 bf16x8;
typedef __attribute__((ext_vector_type(4))) float f32x4;

#define DI   512
#define DO   512
#define XROW (128 * DI)   // floats between consecutive batch rows of x
#define OROW (128 * DO)
#define BK   32

// LDS layouts:
//  A: fp32 [128 m][32 k], 128 B/row = 8 x 16B slots; stored swizzled
//     slot ^= (row>>1)&7 (achieved by pre-swizzling the GLOBAL source of
//     global_load_lds; LDS dest stays linear per m104/m173, rule #21).
//  B: bf16 [128 o][32 k], 64 B/row = 4 x 16B slots; slot ^= (row>>1)&3,
//     applied identically on ds_write and fragment read.
// Both give exact 8-accesses-per-bank cover on b128 ops -> zero conflict.

__global__ __launch_bounds__(512, 4)   // total regs <= 128 -> 4 waves/EU,
                                       // 2 blocks/CU = 16 waves/CU (50%)
void nlinear_mfma(const float* __restrict__ xp, const float* __restrict__ wp,
                  const float* __restrict__ bp, float* __restrict__ op) {
  // XCD swizzle: the 8 tiles of one n land on one XCD (nwg=1024, %8==0)
  int blk = blockIdx.x;
  int L  = ((blk & 7) << 7) + (blk >> 3);
  int n  = L >> 3;
  int mt = (L >> 2) & 1;
  int ot = L & 3;
  int mBase = mt << 7;
  int oBase = ot << 7;

  __shared__ float  aT[128 * 32];   // 16 KB, fp32
  __shared__ __bf16 bT[128 * 32];   // 8 KB, bf16

  int tid  = threadIdx.x;
  int wid  = tid >> 6;              // 8 waves
  int lane = tid & 63;
  int wm  = (wid >> 2) << 6;        // wave m-base: 0/64
  int wn  = (wid & 3) << 5;         // wave o-base: 0/32/64/96
  int l16 = lane & 15;
  int l4  = lane >> 4;

  // ---- A via global_load_lds: wave w covers rows w*16..+16, 2 instrs x 1KB.
  // lane -> row r0+(lane>>3), fetches global 16B-slot g = (lane&7) ^ ((row>>1)&7)
  unsigned aOff[2];
  #pragma unroll
  for (int i = 0; i < 2; ++i) {
    int r0  = (wid << 4) + (i << 3);
    int row = r0 + (lane >> 3);
    int g   = (lane & 7) ^ ((row >> 1) & 7);
    aOff[i] = (unsigned)(((mBase + row) * XROW + n * DI) * 4 + g * 16);
  }

  // ---- B staging: thread t owns ONE o-column, 8 k values (scalar loads,
  // 256B/wave coalesced; k is strided in W so vectors are impossible anyway)
  int bo   = (tid & 63) + (((tid >> 6) & 1) << 6);   // o-column 0..127
  int bks  = (tid >> 7) & 3;                         // k-slot 0..3 (k = 8*bks)
  unsigned bOff = (unsigned)((((unsigned)n * DI + (bks << 3)) * DO + oBase + bo) * 4);
  int bWslot = bks ^ ((bo >> 1) & 3);                // swizzled write slot

  float bReg[8];
  auto loadB = [&](int kt) {
    #pragma unroll
    for (int r = 0; r < 8; ++r)
      bReg[r] = *(const float*)((const char*)wp + bOff + (unsigned)(kt * BK + r) * (DO * 4));
  };
  auto writeB = [&]() {
    bf16x8 v;
    #pragma unroll
    for (int r = 0; r < 8; ++r)
      v[r] = (__bf16)bReg[r];
    *(bf16x8*)((char*)bT + bo * 64 + bWslot * 16) = v;
  };

  auto gloadA = [&](int kt) {
    #pragma unroll
    for (int i = 0; i < 2; ++i) {
      int r0 = (wid << 4) + (i << 3);   // wave-uniform LDS base
      __builtin_amdgcn_global_load_lds(
          (const __attribute__((address_space(1))) void*)
              ((const char*)xp + aOff[i] + (unsigned)(kt * 128)),
          (__attribute__((address_space(3))) void*)((char*)aT + r0 * 128),
          16, 0, 0);
    }
  };

  f32x4 acc[4][2];
  #pragma unroll
  for (int i = 0; i < 4; ++i)
    #pragma unroll
    for (int j = 0; j < 2; ++j)
      acc[i][j] = f32x4{0.f, 0.f, 0.f, 0.f};

  auto compute = [&]() {
    bf16x8 bfr[2];
    #pragma unroll
    for (int j = 0; j < 2; ++j) {
      int row  = wn + j * 16 + l16;
      int slot = l4 ^ ((row >> 1) & 3);
      bfr[j] = *(const bf16x8*)((const char*)bT + row * 64 + slot * 16);
    }
    #pragma unroll
    for (int i = 0; i < 4; ++i) {
      int row = wm + i * 16 + l16;
      int v7  = (row >> 1) & 7;
      const char* rb = (const char*)aT + row * 128;
      f32x4 lo = *(const f32x4*)(rb + (((2 * l4)     ^ v7) * 16));
      f32x4 hi = *(const f32x4*)(rb + (((2 * l4 + 1) ^ v7) * 16));
      bf16x8 a;
      a[0] = (__bf16)lo.x; a[1] = (__bf16)lo.y; a[2] = (__bf16)lo.z; a[3] = (__bf16)lo.w;
      a[4] = (__bf16)hi.x; a[5] = (__bf16)hi.y; a[6] = (__bf16)hi.z; a[7] = (__bf16)hi.w;
      acc[i][0] = __builtin_amdgcn_mfma_f32_16x16x32_bf16(a, bfr[0], acc[i][0], 0, 0, 0);
      acc[i][1] = __builtin_amdgcn_mfma_f32_16x16x32_bf16(a, bfr[1], acc[i][1], 0, 0, 0);
    }
  };

  // bias early; latency hidden under main loop
  float bi[2];
  #pragma unroll
  for (int j = 0; j < 2; ++j)
    bi[j] = bp[n * DO + oBase + wn + j * 16 + l16];

  loadB(0);
  for (int kt = 0; kt < 16; ++kt) {
    __syncthreads();                 // prev compute done reading LDS
    gloadA(kt);                      // DMA x-tile -> aT (fp32, pre-swz source)
    writeB();                        // vmcnt-waits bReg, cvt+write bT
    if (kt < 15) loadB(kt + 1);      // regs renamed; drained at next barrier
    __syncthreads();                 // compiler drains vmcnt(0): aT+bT ready
    compute();
  }

  // epilogue: D layout col = lane&15, row = (lane>>4)*4 + r (m89-verified)
  #pragma unroll
  for (int i = 0; i < 4; ++i) {
    #pragma unroll
    for (int j = 0; j < 2; ++j) {
      #pragma unroll
      for (int r = 0; r < 4; ++r) {
        int m = mBase + wm + i * 16 + l4 * 4 + r;
        int o = oBase + wn + j * 16 + l16;
        op[(size_t)m * OROW + n * DO + o] = acc[i][j][r] + bi[j];
      }
    }
  }
}

extern "C" void kernel_launch(void* const* d_in, const int* in_sizes, int n_in,
                              void* d_out, int out_size, void* d_ws, size_t ws_size,
                              hipStream_t stream) {
  const float* x = (const float*)d_in[0];
  const float* w = (const float*)d_in[1];
  const float* b = (const float*)d_in[2];
  float* o = (float*)d_out;
  hipLaunchKernelGGL(nlinear_mfma, dim3(1024), dim3(512), 0, stream, x, w, b, o);
}

// Round 7
// 53.819 us; speedup vs baseline: 4.2604x; 1.0116x over previous
//
#include <hip/hip_runtime.h>

typedef __attribute__((ext_vector_type(8))) __bf16 bf16x8;
typedef __attribute__((ext_vector_type(4))) float f32x4;

#define DI   512
#define DO   512
#define XROW (128 * DI)   // floats between consecutive batch rows of x
#define OROW (128 * DO)
#define BK   32

// Raw-barrier pipeline primitives (T4): counted vmcnt, never 0 mid-loop.
#define VMCNT(n) asm volatile("s_waitcnt vmcnt(" #n ")" ::: "memory")
#define LGKM0()  asm volatile("s_waitcnt lgkmcnt(0)" ::: "memory")
#define SBAR()   __builtin_amdgcn_s_barrier()
#define SCHED0() __builtin_amdgcn_sched_barrier(0)

// A: fp32 [128 m][32 k], 128 B/row, source-pre-swizzled slot ^= (row>>1)&7
//    (global_load_lds dest must stay linear, rule #21).
// B: bf16 [128 o][32 k], 64 B/row, slot ^= (row>>1)&3 on write and read.

__global__ __launch_bounds__(512, 4)
void nlinear_mfma(const float* __restrict__ xp, const float* __restrict__ wp,
                  const float* __restrict__ bp, float* __restrict__ op) {
  // XCD swizzle: the 8 tiles of one n land on one XCD (nwg=1024, %8==0)
  int blk = blockIdx.x;
  int L  = ((blk & 7) << 7) + (blk >> 3);
  int n  = L >> 3;
  int mt = (L >> 2) & 1;
  int ot = L & 3;
  int mBase = mt << 7;
  int oBase = ot << 7;

  __shared__ float  aT[2][128 * BK];   // 2 x 16 KB fp32
  __shared__ __bf16 bT[2][128 * BK];   // 2 x 8 KB bf16   (48 KB total)

  int tid  = threadIdx.x;
  int wid  = tid >> 6;              // 8 waves
  int lane = tid & 63;
  int wm  = (wid >> 2) << 6;        // wave m-base: 0/64
  int wn  = (wid & 3) << 5;        // wave o-base: 0/32/64/96
  int l16 = lane & 15;
  int l4  = lane >> 4;

  // A DMA: wave w covers rows w*16..+16, 2 instrs x 1KB; lane fetches global
  // 16B-slot g = (lane&7) ^ ((row>>1)&7) so linear LDS ends up swizzled.
  unsigned aOff[2];
  #pragma unroll
  for (int i = 0; i < 2; ++i) {
    int r0  = (wid << 4) + (i << 3);
    int row = r0 + (lane >> 3);
    int g   = (lane & 7) ^ ((row >> 1) & 7);
    aOff[i] = (unsigned)(((mBase + row) * XROW + n * DI) * 4 + g * 16);
  }

  // B staging: thread t owns ONE o-column, 8 k values (scalar, wave-coalesced)
  int bo   = (tid & 63) + (((tid >> 6) & 1) << 6);   // o-column 0..127
  int bks  = (tid >> 7) & 3;                         // k-slot (k = 8*bks)
  unsigned bOff = (unsigned)((((unsigned)n * DI + (bks << 3)) * DO + oBase + bo) * 4);
  int bWslot = bks ^ ((bo >> 1) & 3);

  float bReg[8];
  auto loadB = [&](int kt) {
    #pragma unroll
    for (int r = 0; r < 8; ++r)
      bReg[r] = *(const float*)((const char*)wp + bOff + (unsigned)(kt * BK + r) * (DO * 4));
  };
  auto writeB = [&](int buf) {
    bf16x8 v;
    #pragma unroll
    for (int r = 0; r < 8; ++r)
      v[r] = (__bf16)bReg[r];     // compiler inserts fine-grained vmcnt here
    *(bf16x8*)((char*)bT[buf] + bo * 64 + bWslot * 16) = v;
  };
  auto gloadA = [&](int buf, int kt) {
    #pragma unroll
    for (int i = 0; i < 2; ++i) {
      int r0 = (wid << 4) + (i << 3);
      __builtin_amdgcn_global_load_lds(
          (const __attribute__((address_space(1))) void*)
              ((const char*)xp + aOff[i] + (unsigned)(kt * 128)),
          (__attribute__((address_space(3))) void*)((char*)aT[buf] + r0 * 128),
          16, 0, 0);
    }
  };

  f32x4 acc[4][2];
  #pragma unroll
  for (int i = 0; i < 4; ++i)
    #pragma unroll
    for (int j = 0; j < 2; ++j)
      acc[i][j] = f32x4{0.f, 0.f, 0.f, 0.f};

  auto compute = [&](int buf) {
    bf16x8 bfr[2];
    #pragma unroll
    for (int j = 0; j < 2; ++j) {
      int row  = wn + j * 16 + l16;
      int slot = l4 ^ ((row >> 1) & 3);
      bfr[j] = *(const bf16x8*)((const char*)bT[buf] + row * 64 + slot * 16);
    }
    #pragma unroll
    for (int i = 0; i < 4; ++i) {
      int row = wm + i * 16 + l16;
      int v7  = (row >> 1) & 7;
      const char* rb = (const char*)aT[buf] + row * 128;
      f32x4 lo = *(const f32x4*)(rb + (((2 * l4)     ^ v7) * 16));
      f32x4 hi = *(const f32x4*)(rb + (((2 * l4 + 1) ^ v7) * 16));
      bf16x8 a;
      a[0] = (__bf16)lo.x; a[1] = (__bf16)lo.y; a[2] = (__bf16)lo.z; a[3] = (__bf16)lo.w;
      a[4] = (__bf16)hi.x; a[5] = (__bf16)hi.y; a[6] = (__bf16)hi.z; a[7] = (__bf16)hi.w;
      acc[i][0] = __builtin_amdgcn_mfma_f32_16x16x32_bf16(a, bfr[0], acc[i][0], 0, 0, 0);
      acc[i][1] = __builtin_amdgcn_mfma_f32_16x16x32_bf16(a, bfr[1], acc[i][1], 0, 0, 0);
    }
  };

  float bi[2];
  #pragma unroll
  for (int j = 0; j < 2; ++j)
    bi[j] = bp[n * DO + oBase + wn + j * 16 + l16];

  // ---- prologue: stage tile0, put tile1 in flight ----
  loadB(0);                 // 8 loads
  gloadA(0, 0);             // 2 DMA
  writeB(0);                // auto vmcnt(2): waits B0 regs, A0 DMA stays out
  loadB(1);                 // B1 in flight (regs)
  gloadA(1, 1);             // A1 DMA in flight -> aT[1]
  SCHED0();
  VMCNT(10);                // retire A0 (oldest 2; B1+A1 = 10 stay in flight)
  LGKM0();                  // B0 ds_write visible
  SBAR();
  SCHED0();

  // invariant at top of iter kt: buf[kt&1] complete; A(kt+1) DMA + B(kt+1)
  // regs in flight. vmcnt never drained to 0 until the tail.
  for (int kt = 0; kt < 16; ++kt) {
    int cur = kt & 1;
    compute(cur);
    if (kt < 15) {
      SBAR();               // all waves done reading buf[cur] -> reusable
      SCHED0();
      writeB(cur ^ 1);      // B(kt+1) regs -> bT[nxt] (auto vmcnt(2))
      if (kt < 14) {
        loadB(kt + 2);      // 8 loads
        gloadA(cur, kt + 2);// 2 DMA into the buffer just freed
        SCHED0();
        VMCNT(10);          // retire A(kt+1); keep B(kt+2)+A(kt+2) in flight
      } else {
        SCHED0();
        VMCNT(0);           // tail: only A(15) outstanding
      }
      LGKM0();              // writeB visible
      SBAR();
      SCHED0();
    }
  }

  // epilogue: D layout col = lane&15, row = (lane>>4)*4 + r (m89-verified)
  #pragma unroll
  for (int i = 0; i < 4; ++i) {
    #pragma unroll
    for (int j = 0; j < 2; ++j) {
      #pragma unroll
      for (int r = 0; r < 4; ++r) {
        int m = mBase + wm + i * 16 + l4 * 4 + r;
        int o = oBase + wn + j * 16 + l16;
        op[(size_t)m * OROW + n * DO + o] = acc[i][j][r] + bi[j];
      }
    }
  }
}

extern "C" void kernel_launch(void* const* d_in, const int* in_sizes, int n_in,
                              void* d_out, int out_size, void* d_ws, size_t ws_size,
                              hipStream_t stream) {
  const float* x = (const float*)d_in[0];
  const float* w = (const float*)d_in[1];
  const float* b = (const float*)d_in[2];
  float* o = (float*)d_out;
  hipLaunchKernelGGL(nlinear_mfma, dim3(1024), dim3(512), 0, stream, x, w, b, o);
}